// Round 4
// baseline (637.831 us; speedup 1.0000x reference)
//
#include <hip/hip_runtime.h>
#include <math.h>

#define H   1024
#define H2  2048
#define V   50257
#define L   512
#define NAB 16
#define NB2 256
#define NB3 1024
#define NG3 3142   // ceil(V/16) row-groups of 16

__device__ __forceinline__ float dot4(float4 a, float4 b) {
    return a.x*b.x + a.y*b.y + a.z*b.z + a.w*b.w;
}
__device__ __forceinline__ float wave_red_sum(float v) {
    #pragma unroll
    for (int off = 32; off > 0; off >>= 1) v += __shfl_down(v, off, 64);
    return v;
}
__device__ __forceinline__ float wave_red_max(float v) {
    #pragma unroll
    for (int off = 32; off > 0; off >>= 1) v = fmaxf(v, __shfl_down(v, off, 64));
    return v;
}

// Manual grid barrier: requires all blocks co-resident. Monotonic counter,
// zeroed by the preceding kernel. Release on arrive, acquire after spin.
__device__ __forceinline__ void grid_sync(int* cnt, int target) {
    __syncthreads();
    if (threadIdx.x == 0) {
        __threadfence();   // release all prior writes to device scope
        __hip_atomic_fetch_add(cnt, 1, __ATOMIC_ACQ_REL, __HIP_MEMORY_SCOPE_AGENT);
        while (__hip_atomic_load(cnt, __ATOMIC_ACQUIRE, __HIP_MEMORY_SCOPE_AGENT) < target)
            __builtin_amdgcn_s_sleep(2);
        __threadfence();   // acquire: invalidate stale cached lines
    }
    __syncthreads();
}

// ---- K1: scores[l] = dot(h0, enc[l]); block 0 zeroes sync counters --------
__global__ void __launch_bounds__(256) k_scores(
        const float* __restrict__ h0, const float* __restrict__ enc,
        float* __restrict__ scores, int* __restrict__ cnt) {
    __shared__ float sred[4];
    int t = threadIdx.x, lane = t & 63, wv = t >> 6;
    if (blockIdx.x == 0 && t < 8) cnt[t] = 0;
    int l = blockIdx.x;
    float4 a = ((const float4*)(enc + (size_t)l * H))[t];
    float4 b = ((const float4*)h0)[t];
    float acc = wave_red_sum(dot4(a, b));
    if (lane == 0) sred[wv] = acc;
    __syncthreads();
    if (t == 0) scores[l] = sred[0] + sred[1] + sred[2] + sred[3];
}

// ---- K2: {softmax + attn partials} -> sync -> {combine} -> sync -> {GRU} --
__global__ void __launch_bounds__(256) k_mid(
        const float* __restrict__ enc, const float* __restrict__ scores,
        const int* __restrict__ tok, const float* __restrict__ emb_w,
        const float* __restrict__ Wc, const float* __restrict__ bc,
        const float* __restrict__ w_ih, const float* __restrict__ b_ih,
        const float* __restrict__ w_hh, const float* __restrict__ b_hh,
        const float* __restrict__ h0,
        float* __restrict__ partial, float* __restrict__ xbuf,
        float* __restrict__ hnew, float* __restrict__ d_out,
        int* __restrict__ cnt) {
    __shared__ float wl[L];
    __shared__ float comb[H2];
    __shared__ float sred[4];
    int t = threadIdx.x, lane = t & 63, wv = t >> 6, b = blockIdx.x;

    // P1: redundant softmax in blocks 0..15; block p sums rows [32p, 32p+32)
    if (b < NAB) {
        float s0 = scores[t], s1 = scores[t + 256];
        float m = wave_red_max(fmaxf(s0, s1));
        if (lane == 0) sred[wv] = m;
        __syncthreads();
        float gmax = fmaxf(fmaxf(sred[0], sred[1]), fmaxf(sred[2], sred[3]));
        __syncthreads();
        float e0 = expf(s0 - gmax), e1 = expf(s1 - gmax);
        float ssum = wave_red_sum(e0 + e1);
        if (lane == 0) sred[wv] = ssum;
        __syncthreads();
        float inv = 1.f / (sred[0] + sred[1] + sred[2] + sred[3]);
        float w0 = e0 * inv, w1 = e1 * inv;
        wl[t] = w0; wl[t + 256] = w1;
        if (b == 0) {                         // attn_weights output
            d_out[V + H + t]       = w0;
            d_out[V + H + 256 + t] = w1;
        }
        __syncthreads();
        int r0 = b * 32;
        float4 acc = make_float4(0.f, 0.f, 0.f, 0.f);
        #pragma unroll 8
        for (int k = 0; k < 32; ++k) {
            float w  = wl[r0 + k];
            float4 e = ((const float4*)(enc + (size_t)(r0 + k) * H))[t];
            acc.x += w * e.x; acc.y += w * e.y; acc.z += w * e.z; acc.w += w * e.w;
        }
        ((float4*)(partial + (size_t)b * H))[t] = acc;
    }
    grid_sync(cnt + 0, NB2);

    // P2: sum 16 partials + x = relu([emb, attn] @ Wc^T + bc), 4 rows/block
    {
        float4 a = make_float4(0.f, 0.f, 0.f, 0.f);
        #pragma unroll
        for (int p = 0; p < NAB; ++p) {
            float4 q = ((const float4*)(partial + (size_t)p * H))[t];
            a.x += q.x; a.y += q.y; a.z += q.z; a.w += q.w;
        }
        int tk = tok[0];
        ((float4*)comb)[t]       = ((const float4*)(emb_w + (size_t)tk * H))[t];
        ((float4*)comb)[t + 256] = a;
        __syncthreads();
        int row = b * 4 + wv;
        const float4* wr = (const float4*)(Wc + (size_t)row * H2);
        float acc = 0.f;
        #pragma unroll
        for (int j = 0; j < 8; ++j)
            acc += dot4(wr[j * 64 + lane], ((const float4*)comb)[j * 64 + lane]);
        acc = wave_red_sum(acc);
        if (lane == 0) xbuf[row] = fmaxf(acc + bc[row], 0.f);
    }
    grid_sync(cnt + 1, NB2);

    // P3: GRU unit i = b*4+wv; 6 independent dots, interleaved reduction
    {
        int i = b * 4 + wv;
        const float4* x4 = (const float4*)xbuf;
        const float4* h4 = (const float4*)h0;
        const float4* wi0 = (const float4*)(w_ih + (size_t)i * H);
        const float4* wi1 = (const float4*)(w_ih + (size_t)(H + i) * H);
        const float4* wi2 = (const float4*)(w_ih + (size_t)(2 * H + i) * H);
        const float4* wh0 = (const float4*)(w_hh + (size_t)i * H);
        const float4* wh1 = (const float4*)(w_hh + (size_t)(H + i) * H);
        const float4* wh2 = (const float4*)(w_hh + (size_t)(2 * H + i) * H);
        float ai0 = 0.f, ai1 = 0.f, ai2 = 0.f, ah0 = 0.f, ah1 = 0.f, ah2 = 0.f;
        #pragma unroll
        for (int j = 0; j < 4; ++j) {
            int idx = j * 64 + lane;
            float4 xv = x4[idx], hv = h4[idx];
            ai0 += dot4(wi0[idx], xv);
            ai1 += dot4(wi1[idx], xv);
            ai2 += dot4(wi2[idx], xv);
            ah0 += dot4(wh0[idx], hv);
            ah1 += dot4(wh1[idx], hv);
            ah2 += dot4(wh2[idx], hv);
        }
        #pragma unroll
        for (int off = 32; off > 0; off >>= 1) {
            ai0 += __shfl_down(ai0, off, 64);
            ai1 += __shfl_down(ai1, off, 64);
            ai2 += __shfl_down(ai2, off, 64);
            ah0 += __shfl_down(ah0, off, 64);
            ah1 += __shfl_down(ah1, off, 64);
            ah2 += __shfl_down(ah2, off, 64);
        }
        if (lane == 0) {
            float r = 1.f / (1.f + expf(-(ai0 + b_ih[i]         + ah0 + b_hh[i])));
            float z = 1.f / (1.f + expf(-(ai1 + b_ih[H + i]     + ah1 + b_hh[H + i])));
            float n = tanhf(ai2 + b_ih[2 * H + i] + r * (ah2 + b_hh[2 * H + i]));
            float h = (1.f - z) * n + z * h0[i];
            d_out[V + i] = h;
            hnew[i] = h;
        }
    }
}

// ---- K3: persistent logits + LSE partial -> sync -> combine + subtract ----
// 1024 blocks, launch_bounds(256,4): <=128 VGPR, tiny LDS -> 4 blocks/CU co-resident
__global__ void __launch_bounds__(256, 4) k_out(
        const float* __restrict__ hnew, const float* __restrict__ out_w,
        const float* __restrict__ out_b, float* __restrict__ d_out,
        float* __restrict__ pm, float* __restrict__ ps,
        int* __restrict__ cnt) {
    __shared__ float sm[4], ss[4];
    int t = threadIdx.x, lane = t & 63, wv = t >> 6, b = blockIdx.x;
    const float4* h4 = (const float4*)hnew;

    float m_run = -INFINITY, s_run = 0.f;
    for (int g = b; g < NG3; g += NB3) {
        int base = g * 16 + wv * 4;
        const float4* wr[4];
        #pragma unroll
        for (int r = 0; r < 4; ++r) {
            int row = (base + r < V) ? base + r : V - 1;   // clamp: safe load
            wr[r] = (const float4*)(out_w + (size_t)row * H);
        }
        float a[4] = {0.f, 0.f, 0.f, 0.f};
        #pragma unroll
        for (int j = 0; j < 4; ++j) {
            float4 hv = h4[j * 64 + lane];                 // L2-hot broadcast
            #pragma unroll
            for (int r = 0; r < 4; ++r) a[r] += dot4(wr[r][j * 64 + lane], hv);
        }
        #pragma unroll
        for (int off = 32; off > 0; off >>= 1) {
            #pragma unroll
            for (int r = 0; r < 4; ++r) a[r] += __shfl_down(a[r], off, 64);
        }
        if (lane == 0) {
            #pragma unroll
            for (int r = 0; r < 4; ++r) {
                int row = base + r;
                if (row < V) {
                    float v = a[r] + out_b[row];
                    d_out[row] = v;
                    float mn = fmaxf(m_run, v);
                    s_run = s_run * expf(m_run - mn) + expf(v - mn);
                    m_run = mn;
                }
            }
        }
    }
    if (lane == 0) { sm[wv] = m_run; ss[wv] = s_run; }
    __syncthreads();
    if (t == 0) {
        float M = fmaxf(fmaxf(sm[0], sm[1]), fmaxf(sm[2], sm[3]));
        float S = 0.f;
        #pragma unroll
        for (int k = 0; k < 4; ++k) S += ss[k] * expf(sm[k] - M);
        pm[b] = M; ps[b] = S;
    }
    grid_sync(cnt + 2, NB3);

    // redundant combine of 1024 partials (L2/L3-hot) + in-place subtract
    {
        float m = -INFINITY, s = 0.f;
        #pragma unroll
        for (int k = 0; k < 4; ++k) {
            int i = t * 4 + k;
            float mi = pm[i], si = ps[i];
            float mn = fmaxf(m, mi);
            s = s * expf(m - mn) + si * expf(mi - mn);
            m = mn;
        }
        #pragma unroll
        for (int off = 32; off > 0; off >>= 1) {
            float mo = __shfl_down(m, off, 64);
            float so = __shfl_down(s, off, 64);
            float mn = fmaxf(m, mo);
            s = s * expf(m - mn) + so * expf(mo - mn);
            m = mn;
        }
        if (lane == 0) { sm[wv] = m; ss[wv] = s; }
        __syncthreads();
        float M = fmaxf(fmaxf(sm[0], sm[1]), fmaxf(sm[2], sm[3]));
        float S = 0.f;
        #pragma unroll
        for (int k = 0; k < 4; ++k) S += ss[k] * expf(sm[k] - M);
        float off = M + logf(S);
        int i = b * 256 + t;
        if (i < V) d_out[i] -= off;
    }
}

extern "C" void kernel_launch(void* const* d_in, const int* in_sizes, int n_in,
                              void* d_out, int out_size, void* d_ws, size_t ws_size,
                              hipStream_t stream) {
    const int*   tok    = (const int*)d_in[0];
    const float* hidden = (const float*)d_in[1];
    const float* enc    = (const float*)d_in[2];
    const float* emb_w  = (const float*)d_in[3];
    const float* Wc     = (const float*)d_in[4];
    const float* bc     = (const float*)d_in[5];
    const float* w_ih   = (const float*)d_in[6];
    const float* w_hh   = (const float*)d_in[7];
    const float* b_ih   = (const float*)d_in[8];
    const float* b_hh   = (const float*)d_in[9];
    const float* out_w  = (const float*)d_in[10];
    const float* out_b  = (const float*)d_in[11];
    float* out = (float*)d_out;
    float* ws  = (float*)d_ws;

    float* scores  = ws;             // 512  (pad to 1024)
    float* partial = ws + 1024;      // 16*1024
    float* xbuf    = ws + 17408;     // 1024
    float* hnew    = ws + 18432;     // 1024
    float* pm      = ws + 19456;     // 1024
    float* psum    = ws + 20480;     // 1024
    int*   cnt     = (int*)(ws + 21504); // 8 ints

    k_scores<<<512, 256, 0, stream>>>(hidden, enc, scores, cnt);
    k_mid   <<<NB2, 256, 0, stream>>>(enc, scores, tok, emb_w, Wc, bc,
                                      w_ih, b_ih, w_hh, b_hh, hidden,
                                      partial, xbuf, hnew, out, cnt);
    k_out   <<<NB3, 256, 0, stream>>>(hnew, out_w, out_b, out, pm, psum, cnt);
}